// Round 6
// baseline (335.416 us; speedup 1.0000x reference)
//
#include <hip/hip_runtime.h>

// ---------------------------------------------------------------------------
// sxsGCN: h=[B=128,N=4096,3]; 3x { relu((adj@h)@W+b) }; then FC 12288->54->4096
// bf16 MFMA GEMMs adj[4096x4096] @ H[4096 x B*F], H stored transposed.
// R1: fc1 split-K + atomics: 275us -> ~10us.
// R2: gemm double-buffered BK=64: 62 -> 47us.
// R3: XOR-swizzled LDS (conflicts 4.2e6 -> 0), flat => feed-bound not LDS.
// R4: 128x128 tiles + XCD swizzle + split-K atomics: FETCH 133->33MB (A hits
//     HBM once, B served by L3) BUT 256-288 blocks = 1 block/CU -> occupancy
//     10%, every barrier drain naked: 47 -> 53us. Lesson: traffic fix needs
//     >=2 blocks/CU to matter.
// R5: deeper split-K only (CT=3:KS=8, CT=4:KS=6 -> 768 blocks = 3/CU).
//     Split-K partitions k so A/B logical traffic unchanged; only C atomics
//     scale (L2-resident). Predict gemm 53 -> ~23us, occupancy ~30%.
// ---------------------------------------------------------------------------

typedef __bf16 bf16x8 __attribute__((ext_vector_type(8)));
typedef float  f32x4  __attribute__((ext_vector_type(4)));

#define N_NODE 4096
#define BATCH  128

__device__ __forceinline__ void async_copy16(const void* gsrc, void* ldst) {
    __builtin_amdgcn_global_load_lds(
        (const __attribute__((address_space(1))) void*)gsrc,
        (__attribute__((address_space(3))) void*)ldst,
        16, 0, 0);
}

// prep: [0,8192) cast adj->bf16 | [8192,9728) build H0 | [9728,9755) zero hid
//       | [9755,11803) zero C (8 MB)
__global__ __launch_bounds__(256) void prep_k(const float* __restrict__ adj,
                                              __bf16* __restrict__ adjB,
                                              const float* __restrict__ X,
                                              __bf16* __restrict__ H0,
                                              float* __restrict__ hid_acc,
                                              float* __restrict__ C) {
    const int blk = blockIdx.x, tx = threadIdx.x;
    if (blk < 8192) {
        const size_t i = (size_t)blk * 256 + tx;       // group of 8
        const float4* a4 = (const float4*)adj;
        float4 u = a4[i * 2];
        float4 v = a4[i * 2 + 1];
        bf16x8 o = { (__bf16)u.x, (__bf16)u.y, (__bf16)u.z, (__bf16)u.w,
                     (__bf16)v.x, (__bf16)v.y, (__bf16)v.z, (__bf16)v.w };
        *(bf16x8*)(adjB + i * 8) = o;
    } else if (blk < 9728) {
        const int base = (blk - 8192) * 1024;
#pragma unroll
        for (int k = 0; k < 4; ++k) {
            const int idx = base + k * 256 + tx;       // < 384*4096
            const int c = idx >> 12, m = idx & 4095;
            const int b = c / 3, f = c - b * 3;
            H0[idx] = (__bf16)X[(size_t)b * 12288 + m * 3 + f];
        }
    } else if (blk < 9755) {
        const int i = (blk - 9728) * 256 + tx;
        if (i < BATCH * 54) hid_acc[i] = 0.f;
    } else {
        const int i = (blk - 9755) * 256 + tx;         // < 2048*256
        ((float4*)C)[i] = float4{0.f, 0.f, 0.f, 0.f};
    }
}

// C[m][c] += sum_{k in split} adjB[m][k] * Ht[c][k]
// 128x128 tile, 4 waves (2x2, each 64x64 via 4x4 16x16x32 MFMAs), BK=32,
// double-buffered LDS with XOR-swizzled 16B-chunk placement
// (pos = (chunk + (row>>1)) & 3 -> 2 lanes/bank = free).
// XCD swizzle: l%8 = xcd; per-xcd sequence covers 4 m-bands x CT x KS, so all
// c/ks-variants of an m-band share one XCD's L2.
// C stride fixed 512; split-K partials accumulated with atomicAdd.
template <int CT, int KS>
__global__ __launch_bounds__(256) void gemm_k(const __bf16* __restrict__ A,
                                              const __bf16* __restrict__ Bt,
                                              float* __restrict__ C) {
    __shared__ __align__(16) __bf16 As[2 * 4096];   // [buf][128 rows][32 k]
    __shared__ __align__(16) __bf16 Bs[2 * 4096];
    const int tx   = threadIdx.x;
    const int wave = tx >> 6, lane = tx & 63;
    const int quad = lane >> 4, lr = lane & 15;

    const int l = blockIdx.x;
    const int xcd = l & 7, s = l >> 3;
    const int mi = xcd * 4 + (s & 3);
    const int r2 = s >> 2;
    const int ci = r2 % CT, ks = r2 / CT;
    const int m0 = mi * 128, c0 = ci * 128;
    const int kb = (128 * ks) / KS, ke = (128 * (ks + 1)) / KS;  // BK=32 units

    const int wm = wave >> 1, wn = wave & 1;

    // staging: thread t owns chunks {t, t+256}; chunk ch -> row=ch>>2,
    // pos=ch&3, logical k-chunk lc=(pos-(row>>1))&3; LDS slot = ch*16B.
    const int r0 = tx >> 2,        p0 = tx & 3,        lc0 = (p0 - (r0 >> 1)) & 3;
    const int r1 = (tx + 256) >> 2, p1 = (tx + 256) & 3, lc1 = (p1 - (r1 >> 1)) & 3;
    const __bf16* gA0 = A  + (size_t)(m0 + r0) * 4096 + lc0 * 8;
    const __bf16* gA1 = A  + (size_t)(m0 + r1) * 4096 + lc1 * 8;
    const __bf16* gB0 = Bt + (size_t)(c0 + r0) * 4096 + lc0 * 8;
    const __bf16* gB1 = Bt + (size_t)(c0 + r1) * 4096 + lc1 * 8;
    __bf16* lA0 = &As[tx * 8];        __bf16* lA1 = &As[tx * 8 + 2048];
    __bf16* lB0 = &Bs[tx * 8];        __bf16* lB1 = &Bs[tx * 8 + 2048];

    // reader swizzle position: independent of i (i*16>>1 = 8i == 0 mod 4)
    const int apos  = (quad + (lr >> 1)) & 3;
    const int abase = (wm * 64 + lr) * 32 + apos * 8;
    const int bbase = (wn * 64 + lr) * 32 + apos * 8;

    f32x4 acc[4][4] = {};

    // prologue: stage tile kb into buf 0
    {
        const int k0 = kb * 32;
        async_copy16(gA0 + k0, lA0);
        async_copy16(gA1 + k0, lA1);
        async_copy16(gB0 + k0, lB0);
        async_copy16(gB1 + k0, lB1);
    }

    int buf = 0;
    for (int kt = kb; kt < ke; ++kt) {
        __syncthreads();            // drains vmcnt -> buf ready
        if (kt + 1 < ke) {
            const int k0 = (kt + 1) * 32;
            const int bo = (buf ^ 1) * 4096;
            async_copy16(gA0 + k0, lA0 + bo);
            async_copy16(gA1 + k0, lA1 + bo);
            async_copy16(gB0 + k0, lB0 + bo);
            async_copy16(gB1 + k0, lB1 + bo);
        }
        const int bo = buf * 4096;
        bf16x8 af[4], bfv[4];
#pragma unroll
        for (int i = 0; i < 4; ++i) af[i]  = *(const bf16x8*)(&As[bo + abase + i * 512]);
#pragma unroll
        for (int j = 0; j < 4; ++j) bfv[j] = *(const bf16x8*)(&Bs[bo + bbase + j * 512]);
#pragma unroll
        for (int i = 0; i < 4; ++i)
#pragma unroll
            for (int j = 0; j < 4; ++j)
                acc[i][j] = __builtin_amdgcn_mfma_f32_16x16x32_bf16(af[i], bfv[j], acc[i][j], 0, 0, 0);
        buf ^= 1;
    }

#pragma unroll
    for (int i = 0; i < 4; ++i)
#pragma unroll
        for (int j = 0; j < 4; ++j)
#pragma unroll
            for (int r = 0; r < 4; ++r) {
                const int row = m0 + wm * 64 + i * 16 + quad * 4 + r;
                const int col = c0 + wn * 64 + j * 16 + lr;
                atomicAdd(&C[(size_t)row * 512 + col], acc[i][j][r]);
            }
}

// Coalesced transpose epilogue; REZERO writes C back to 0 for the next
// split-K GEMM (each block owns its C tile exclusively).
template <int FI, int FO, typename OUT_T, bool REZERO>
__global__ __launch_bounds__(256) void epi_k(float* __restrict__ C,
                                             const float* __restrict__ W,
                                             const float* __restrict__ bias,
                                             OUT_T* __restrict__ Hout) {
    constexpr int COLS = 32 * FI;
    constexpr int S    = COLS + 1;
    __shared__ float ld[64 * S];
    const int tx = threadIdx.x;
    const int m0  = blockIdx.x * 64;
    const int bt0 = blockIdx.y * 32;

    for (int idx = tx; idx < 64 * COLS; idx += 256) {
        const int r = idx / COLS, cc = idx - r * COLS;
        ld[r * S + cc] = C[(size_t)(m0 + r) * 512 + bt0 * FI + cc];
        if (REZERO) C[(size_t)(m0 + r) * 512 + bt0 * FI + cc] = 0.f;
    }
    __syncthreads();

    const int m_l = tx & 63, bq = tx >> 6;
    float Wl[FI][FO];
#pragma unroll
    for (int fi = 0; fi < FI; ++fi)
#pragma unroll
        for (int fo = 0; fo < FO; ++fo) Wl[fi][fo] = W[fi * FO + fo];

#pragma unroll
    for (int p = 0; p < 8; ++p) {
        const int bl = bq + p * 4;
        float in[FI];
#pragma unroll
        for (int fi = 0; fi < FI; ++fi) in[fi] = ld[m_l * S + bl * FI + fi];
#pragma unroll
        for (int fo = 0; fo < FO; ++fo) {
            float v = bias[fo];
#pragma unroll
            for (int fi = 0; fi < FI; ++fi) v += in[fi] * Wl[fi][fo];
            v = fmaxf(v, 0.f);
            Hout[(size_t)((bt0 + bl) * FO + fo) * N_NODE + m0 + m_l] = (OUT_T)v;
        }
    }
}

// fc1 split-K partial sums: grid (64 n-chunks, 8 b-groups of 16).
__global__ __launch_bounds__(256) void fc1p_k(const float* __restrict__ H3,
                                              const float* __restrict__ Wfc,
                                              float* __restrict__ hid_acc) {
    __shared__ float hs[16 * 192];       // [b][f][n]
    __shared__ float red[4][16][64];
    const int tx = threadIdx.x;
    const int wv = tx >> 6, lane = tx & 63;
    const int n0 = blockIdx.x * 64;
    const int b0 = blockIdx.y * 16;

    for (int idx = tx; idx < 3072; idx += 256) {
        const int n = idx & 63, f = (idx >> 6) % 3, b = idx / 192;
        hs[idx] = H3[((size_t)((b0 + b) * 3 + f)) * N_NODE + n0 + n];
    }
    __syncthreads();

    float acc[16];
#pragma unroll
    for (int b = 0; b < 16; ++b) acc[b] = 0.f;
    if (lane < 54) {
        const int nb = wv * 16;
        for (int n = 0; n < 16; ++n) {
#pragma unroll
            for (int f = 0; f < 3; ++f) {
                const float w = Wfc[((size_t)(n0 + nb + n) * 3 + f) * 54 + lane];
#pragma unroll
                for (int b = 0; b < 16; ++b)
                    acc[b] += hs[b * 192 + f * 64 + nb + n] * w;
            }
        }
    }
#pragma unroll
    for (int b = 0; b < 16; ++b) red[wv][b][lane] = acc[b];
    __syncthreads();
    if (wv == 0 && lane < 54) {
        for (int b = 0; b < 16; ++b) {
            const float s = red[0][b][lane] + red[1][b][lane] +
                            red[2][b][lane] + red[3][b][lane];
            atomicAdd(&hid_acc[(b0 + b) * 54 + lane], s);
        }
    }
}

// out[b][a] = sum_j relu(hid_acc[b][j]+bfc[j]) * Wout[j][a] + bout[a]
__global__ __launch_bounds__(256) void fc2_k(const float* __restrict__ hid_acc,
                                             const float* __restrict__ bfc,
                                             const float* __restrict__ Wout,
                                             const float* __restrict__ bout,
                                             float* __restrict__ out) {
    const int tx = threadIdx.x;
    const int a  = blockIdx.x * 256 + tx;
    const int b0 = blockIdx.y * 4;
    __shared__ float hs[4 * 54];
    if (tx < 216) {
        const int j = tx % 54;
        hs[tx] = fmaxf(hid_acc[b0 * 54 + tx] + bfc[j], 0.f);
    }
    __syncthreads();
    float a0 = 0.f, a1 = 0.f, a2 = 0.f, a3 = 0.f;
    for (int j = 0; j < 54; ++j) {
        float w = Wout[(size_t)j * N_NODE + a];
        a0 += hs[0 * 54 + j] * w;
        a1 += hs[1 * 54 + j] * w;
        a2 += hs[2 * 54 + j] * w;
        a3 += hs[3 * 54 + j] * w;
    }
    float bo = bout[a];
    out[(size_t)(b0 + 0) * N_NODE + a] = a0 + bo;
    out[(size_t)(b0 + 1) * N_NODE + a] = a1 + bo;
    out[(size_t)(b0 + 2) * N_NODE + a] = a2 + bo;
    out[(size_t)(b0 + 3) * N_NODE + a] = a3 + bo;
}

extern "C" void kernel_launch(void* const* d_in, const int* in_sizes, int n_in,
                              void* d_out, int out_size, void* d_ws, size_t ws_size,
                              hipStream_t stream) {
    const float* X    = (const float*)d_in[0];
    const float* adj  = (const float*)d_in[1];
    const float* W1   = (const float*)d_in[2];
    const float* b1   = (const float*)d_in[3];
    const float* W2   = (const float*)d_in[4];
    const float* b2   = (const float*)d_in[5];
    const float* W3   = (const float*)d_in[6];
    const float* b3   = (const float*)d_in[7];
    const float* Wfc  = (const float*)d_in[8];
    const float* bfc  = (const float*)d_in[9];
    const float* Wout = (const float*)d_in[10];
    const float* bout = (const float*)d_in[11];
    float* out = (float*)d_out;

    // ws: adjB 32MB | P1 4MB (H0/H2 bf16) | P2 6MB (H1 bf16 / H3 fp32)
    //   | C fp32 [4096][512] 8MB (atomic acc, stride 512 all stages) | hid
    char* w = (char*)d_ws;
    __bf16* adjB = (__bf16*)w;
    __bf16* P1   = (__bf16*)(w + 33554432);
    char*   P2   = w + 33554432 + 4194304;
    float*  C    = (float*)(w + 33554432 + 4194304 + 6291456);
    float*  hid  = (float*)(w + 33554432 + 4194304 + 6291456 + 8388608);

    __bf16* H0 = P1;
    __bf16* H1 = (__bf16*)P2;
    __bf16* H2 = P1;
    float*  H3 = (float*)P2;

    prep_k<<<11803, 256, 0, stream>>>(adj, adjB, X, H0, hid, C);

    // stage 1: Nc=384 -> CT=3, KS=8 (768 blocks = 3/CU, 16-iter k-chunks)
    gemm_k<3, 8><<<768, 256, 0, stream>>>(adjB, H0, C);
    epi_k<3, 4, __bf16, true><<<dim3(64, 4), 256, 0, stream>>>(C, W1, b1, H1);

    // stage 2: Nc=512 -> CT=4, KS=6 (768 blocks = 3/CU)
    gemm_k<4, 6><<<768, 256, 0, stream>>>(adjB, H1, C);
    epi_k<4, 4, __bf16, true><<<dim3(64, 4), 256, 0, stream>>>(C, W2, b2, H2);

    // stage 3: Nc=512
    gemm_k<4, 6><<<768, 256, 0, stream>>>(adjB, H2, C);
    epi_k<4, 3, float, false><<<dim3(64, 4), 256, 0, stream>>>(C, W3, b3, H3);

    // FC head
    fc1p_k<<<dim3(64, 8), 256, 0, stream>>>(H3, Wfc, hid);
    fc2_k<<<dim3(16, 32), 256, 0, stream>>>(hid, bfc, Wout, bout, out);
}

// Round 7
// 233.668 us; speedup vs baseline: 1.4354x; 1.4354x over previous
//
#include <hip/hip_runtime.h>

// ---------------------------------------------------------------------------
// sxsGCN: h=[B=128,N=4096,3]; 3x { relu((adj@h)@W+b) }; then FC 12288->54->4096
// bf16 MFMA GEMMs adj[4096x4096] @ H[4096 x 512], H transposed [b*4+f][m].
// R1: fc1 split-K + atomics: 275us -> ~15us.
// R2: gemm double-buffered BK=64: 62 -> 47us.
// R3: XOR-swizzled LDS (conflicts 4.2e6 -> 0): feed/latency-bound, not LDS.
// R4: 128x128+split-K atomics: FETCH 133->33MB but 1 block/CU: 53us. FAIL.
// R5: deeper split-K: atomic epilogue x3, short k-chunks: 61.5us. FAIL.
// R6: restructure. (adj@h)@W == adj@(h@W): W1 folded into prep (G0=X@W1,
//     512 cols -> uniform whole-batch 64-col tiles), W2*W3 chained in stage-2
//     epilogue (stage-3 input padded f=4 w/ zero col). Epilogues FUSED into
//     the gemm (LDS transpose stride-65, in-register tiny linear, coalesced
//     H writes): no C buffer, no atomics, 9 -> 6 dispatches (~100us of wall
//     was inter-dispatch overhead). GEMM core = R3's proven K-loop + XCD
//     swizzle.
// ---------------------------------------------------------------------------

typedef __bf16 bf16x8 __attribute__((ext_vector_type(8)));
typedef float  f32x4  __attribute__((ext_vector_type(4)));

#define N_NODE 4096
#define BATCH  128

__device__ __forceinline__ void async_copy16(const void* gsrc, void* ldst) {
    __builtin_amdgcn_global_load_lds(
        (const __attribute__((address_space(1))) void*)gsrc,
        (__attribute__((address_space(3))) void*)ldst,
        16, 0, 0);
}

// prep: [0,8192) cast adj->bf16 | [8192,10240) G0[b*4+f][m] = (X@W1)^T bf16
//       | [10240,10267) zero hid
__global__ __launch_bounds__(256) void prep_k(const float* __restrict__ adj,
                                              __bf16* __restrict__ adjB,
                                              const float* __restrict__ X,
                                              const float* __restrict__ W1,
                                              __bf16* __restrict__ G0,
                                              float* __restrict__ hid_acc) {
    const int blk = blockIdx.x, tx = threadIdx.x;
    if (blk < 8192) {
        const size_t i = (size_t)blk * 256 + tx;       // group of 8
        const float4* a4 = (const float4*)adj;
        float4 u = a4[i * 2];
        float4 v = a4[i * 2 + 1];
        bf16x8 o = { (__bf16)u.x, (__bf16)u.y, (__bf16)u.z, (__bf16)u.w,
                     (__bf16)v.x, (__bf16)v.y, (__bf16)v.z, (__bf16)v.w };
        *(bf16x8*)(adjB + i * 8) = o;
    } else if (blk < 10240) {
        const int base = (blk - 8192) * 1024;          // c uniform per block
        const int c = base >> 12, b = c >> 2, f = c & 3;
        const float w0 = W1[0 * 4 + f], w1 = W1[1 * 4 + f], w2 = W1[2 * 4 + f];
        const float* Xb = X + (size_t)b * 12288;
#pragma unroll
        for (int k = 0; k < 4; ++k) {
            const int idx = base + k * 256 + tx;       // < 512*4096
            const int m = idx & 4095;
            const float v = Xb[m * 3 + 0] * w0 + Xb[m * 3 + 1] * w1 + Xb[m * 3 + 2] * w2;
            G0[idx] = (__bf16)v;
        }
    } else {
        const int i = (blk - 10240) * 256 + tx;
        if (i < BATCH * 54) hid_acc[i] = 0.f;
    }
}

// Fused GEMM + epilogue. C[m][c] = sum_k adjB[m][k] * Ht[c][k], tile 64x64,
// 4 waves of 32x32, BK=64 double-buffered, XOR-swizzled LDS (R3 core).
// Epilogue: C-tile -> LDS (stride 65, conflict-free), then per-(m,b):
//   MODE 0 (stage1): h1 = relu(C + b1[f])                       -> Hout bf16
//   MODE 1 (stage2): g2 = relu(C@W2 + b2) @ W3, f=3 col zeroed  -> Hout bf16
//   MODE 2 (stage3): h3 = relu(C + b3[f]), f<3                  -> H3out fp32
// XCD swizzle: l&7 = xcd; mi = xcd*8 + (s&7), ci = s>>3 -> 8 m-band blocks
// sharing a B-tile run on one XCD (working set ~4.5MB ~ L2).
template <int MODE>
__global__ __launch_bounds__(256) void gcn_k(const __bf16* __restrict__ A,
                                             const __bf16* __restrict__ Bt,
                                             const float* __restrict__ Wa,
                                             const float* __restrict__ ba,
                                             const float* __restrict__ Wb,
                                             __bf16* __restrict__ Hout,
                                             float* __restrict__ H3out) {
    // [mat][buf][khalf][64 rows][32 k]; reused as float Ct[64][65] in epilogue
    __shared__ __align__(16) __bf16 smem[2][2][2][2048];
    const int tx   = threadIdx.x;
    const int wave = tx >> 6, lane = tx & 63;
    const int quad = lane >> 4, lr = lane & 15;

    const int l = blockIdx.x;
    const int xcd = l & 7, s = l >> 3;
    const int mi = xcd * 8 + (s & 7), ci = s >> 3;
    const int m0 = mi * 64, c0 = ci * 64;
    const int wm = wave >> 1, wn = wave & 1;   // 32x32 quadrant per wave

    // staging: thread t owns LDS slot t*16B = (row=t>>2, pos=t&3); fetches
    // logical k-chunk lc = (pos - (row>>1)) & 3 of its row.
    const int srow   = tx >> 2;
    const int schunk = ((tx & 3) - (srow >> 1)) & 3;
    const int skoff  = schunk * 8;
    const __bf16* gA = A  + (size_t)(m0 + srow) * 4096 + skoff;
    const __bf16* gB = Bt + (size_t)(c0 + srow) * 4096 + skoff;
    __bf16* lA0_ = &smem[0][0][0][tx * 8];  __bf16* lA1_ = &smem[0][0][1][tx * 8];
    __bf16* lB0_ = &smem[1][0][0][tx * 8];  __bf16* lB1_ = &smem[1][0][1][tx * 8];
    const int bufstride = 4096;

    // reader swizzle: pos = (quad + (row>>1))&3, independent of i (16i>>1 % 4 == 0)
    const int pos = (quad + (lr >> 1)) & 3;
    const int arow0 = (wm * 32 + lr) * 32 + pos * 8;
    const int brow0 = (wn * 32 + lr) * 32 + pos * 8;

    f32x4 acc[2][2] = {};

    async_copy16(gA,      lA0_);
    async_copy16(gA + 32, lA1_);
    async_copy16(gB,      lB0_);
    async_copy16(gB + 32, lB1_);

    int buf = 0;
    for (int kt = 0; kt < 64; ++kt) {
        __syncthreads();                 // drains vmcnt -> buf ready
        if (kt + 1 < 64) {
            const int ko = (kt + 1) * 64;
            const int bo = (buf ^ 1) * bufstride;
            async_copy16(gA + ko,      lA0_ + bo);
            async_copy16(gA + ko + 32, lA1_ + bo);
            async_copy16(gB + ko,      lB0_ + bo);
            async_copy16(gB + ko + 32, lB1_ + bo);
        }
#pragma unroll
        for (int kh = 0; kh < 2; ++kh) {
            bf16x8 a0  = *(const bf16x8*)(&smem[0][buf][kh][arow0]);
            bf16x8 a1  = *(const bf16x8*)(&smem[0][buf][kh][arow0 + 512]);
            bf16x8 b0v = *(const bf16x8*)(&smem[1][buf][kh][brow0]);
            bf16x8 b1v = *(const bf16x8*)(&smem[1][buf][kh][brow0 + 512]);
            acc[0][0] = __builtin_amdgcn_mfma_f32_16x16x32_bf16(a0, b0v, acc[0][0], 0, 0, 0);
            acc[0][1] = __builtin_amdgcn_mfma_f32_16x16x32_bf16(a0, b1v, acc[0][1], 0, 0, 0);
            acc[1][0] = __builtin_amdgcn_mfma_f32_16x16x32_bf16(a1, b0v, acc[1][0], 0, 0, 0);
            acc[1][1] = __builtin_amdgcn_mfma_f32_16x16x32_bf16(a1, b1v, acc[1][1], 0, 0, 0);
        }
        buf ^= 1;
    }

    // ---- fused epilogue ----
    __syncthreads();                     // all LDS reads of K-loop done
    float* Ct = (float*)smem;            // [64][65]
#pragma unroll
    for (int i = 0; i < 2; ++i)
#pragma unroll
        for (int j = 0; j < 2; ++j)
#pragma unroll
            for (int r = 0; r < 4; ++r)
                Ct[(wm * 32 + i * 16 + quad * 4 + r) * 65 + wn * 32 + j * 16 + lr] = acc[i][j][r];
    __syncthreads();

    const int m_l = tx & 63, bq = tx >> 6;   // 64 cols = 16 whole batches (FI=4)
    if (MODE == 0) {
        const float b0f = ba[0], b1f = ba[1], b2f = ba[2], b3f = ba[3];
#pragma unroll
        for (int q = 0; q < 4; ++q) {
            const int bl = bq * 4 + q;
            const float* row = &Ct[m_l * 65 + bl * 4];
            __bf16* o = Hout + (size_t)(c0 + bl * 4) * N_NODE + m0 + m_l;
            o[0 * N_NODE] = (__bf16)fmaxf(row[0] + b0f, 0.f);
            o[1 * N_NODE] = (__bf16)fmaxf(row[1] + b1f, 0.f);
            o[2 * N_NODE] = (__bf16)fmaxf(row[2] + b2f, 0.f);
            o[3 * N_NODE] = (__bf16)fmaxf(row[3] + b3f, 0.f);
        }
    } else if (MODE == 1) {
        float W2l[16], W3l[12], bl2[4];
#pragma unroll
        for (int i = 0; i < 16; ++i) W2l[i] = Wa[i];
#pragma unroll
        for (int i = 0; i < 12; ++i) W3l[i] = Wb[i];
#pragma unroll
        for (int i = 0; i < 4; ++i) bl2[i] = ba[i];
#pragma unroll
        for (int q = 0; q < 4; ++q) {
            const int bl = bq * 4 + q;
            const float* row = &Ct[m_l * 65 + bl * 4];
            float tmp[4];
#pragma unroll
            for (int fo = 0; fo < 4; ++fo)
                tmp[fo] = fmaxf(row[0] * W2l[fo] + row[1] * W2l[4 + fo] +
                                row[2] * W2l[8 + fo] + row[3] * W2l[12 + fo] + bl2[fo], 0.f);
            __bf16* o = Hout + (size_t)(c0 + bl * 4) * N_NODE + m0 + m_l;
#pragma unroll
            for (int f3 = 0; f3 < 3; ++f3)
                o[f3 * N_NODE] = (__bf16)(tmp[0] * W3l[f3] + tmp[1] * W3l[3 + f3] +
                                          tmp[2] * W3l[6 + f3] + tmp[3] * W3l[9 + f3]);
            o[3 * N_NODE] = (__bf16)0.f;     // pad column for stage-3 gemm
        }
    } else {
        const float b0f = ba[0], b1f = ba[1], b2f = ba[2];
#pragma unroll
        for (int q = 0; q < 4; ++q) {
            const int bl = bq * 4 + q;
            const int b = ci * 16 + bl;
            const float* row = &Ct[m_l * 65 + bl * 4];
            float* o = H3out + (size_t)(b * 3) * N_NODE + m0 + m_l;
            o[0 * N_NODE] = fmaxf(row[0] + b0f, 0.f);
            o[1 * N_NODE] = fmaxf(row[1] + b1f, 0.f);
            o[2 * N_NODE] = fmaxf(row[2] + b2f, 0.f);
        }
    }
}

// fc1 split-K partial sums: grid (64 n-chunks, 8 b-groups of 16).
__global__ __launch_bounds__(256) void fc1p_k(const float* __restrict__ H3,
                                              const float* __restrict__ Wfc,
                                              float* __restrict__ hid_acc) {
    __shared__ float hs[16 * 192];       // [b][f][n]
    __shared__ float red[4][16][64];
    const int tx = threadIdx.x;
    const int wv = tx >> 6, lane = tx & 63;
    const int n0 = blockIdx.x * 64;
    const int b0 = blockIdx.y * 16;

    for (int idx = tx; idx < 3072; idx += 256) {
        const int n = idx & 63, f = (idx >> 6) % 3, b = idx / 192;
        hs[idx] = H3[((size_t)((b0 + b) * 3 + f)) * N_NODE + n0 + n];
    }
    __syncthreads();

    float acc[16];
#pragma unroll
    for (int b = 0; b < 16; ++b) acc[b] = 0.f;
    if (lane < 54) {
        const int nb = wv * 16;
        for (int n = 0; n < 16; ++n) {
#pragma unroll
            for (int f = 0; f < 3; ++f) {
                const float w = Wfc[((size_t)(n0 + nb + n) * 3 + f) * 54 + lane];
#pragma unroll
                for (int b = 0; b < 16; ++b)
                    acc[b] += hs[b * 192 + f * 64 + nb + n] * w;
            }
        }
    }
#pragma unroll
    for (int b = 0; b < 16; ++b) red[wv][b][lane] = acc[b];
    __syncthreads();
    if (wv == 0 && lane < 54) {
        for (int b = 0; b < 16; ++b) {
            const float s = red[0][b][lane] + red[1][b][lane] +
                            red[2][b][lane] + red[3][b][lane];
            atomicAdd(&hid_acc[(b0 + b) * 54 + lane], s);
        }
    }
}

// out[b][a] = sum_j relu(hid_acc[b][j]+bfc[j]) * Wout[j][a] + bout[a]
__global__ __launch_bounds__(256) void fc2_k(const float* __restrict__ hid_acc,
                                             const float* __restrict__ bfc,
                                             const float* __restrict__ Wout,
                                             const float* __restrict__ bout,
                                             float* __restrict__ out) {
    const int tx = threadIdx.x;
    const int a  = blockIdx.x * 256 + tx;
    const int b0 = blockIdx.y * 4;
    __shared__ float hs[4 * 54];
    if (tx < 216) {
        const int j = tx % 54;
        hs[tx] = fmaxf(hid_acc[b0 * 54 + tx] + bfc[j], 0.f);
    }
    __syncthreads();
    float a0 = 0.f, a1 = 0.f, a2 = 0.f, a3 = 0.f;
    for (int j = 0; j < 54; ++j) {
        float w = Wout[(size_t)j * N_NODE + a];
        a0 += hs[0 * 54 + j] * w;
        a1 += hs[1 * 54 + j] * w;
        a2 += hs[2 * 54 + j] * w;
        a3 += hs[3 * 54 + j] * w;
    }
    float bo = bout[a];
    out[(size_t)(b0 + 0) * N_NODE + a] = a0 + bo;
    out[(size_t)(b0 + 1) * N_NODE + a] = a1 + bo;
    out[(size_t)(b0 + 2) * N_NODE + a] = a2 + bo;
    out[(size_t)(b0 + 3) * N_NODE + a] = a3 + bo;
}

extern "C" void kernel_launch(void* const* d_in, const int* in_sizes, int n_in,
                              void* d_out, int out_size, void* d_ws, size_t ws_size,
                              hipStream_t stream) {
    const float* X    = (const float*)d_in[0];
    const float* adj  = (const float*)d_in[1];
    const float* W1   = (const float*)d_in[2];
    const float* b1   = (const float*)d_in[3];
    const float* W2   = (const float*)d_in[4];
    const float* b2   = (const float*)d_in[5];
    const float* W3   = (const float*)d_in[6];
    const float* b3   = (const float*)d_in[7];
    const float* Wfc  = (const float*)d_in[8];
    const float* bfc  = (const float*)d_in[9];
    const float* Wout = (const float*)d_in[10];
    const float* bout = (const float*)d_in[11];
    float* out = (float*)d_out;

    // ws: adjB 32MB | G0 bf16 [512][4096] 4MB | H1 bf16 4MB | H2g bf16 4MB
    //   | H3 fp32 [384][4096] 6MB | hid [128][54]
    char* w = (char*)d_ws;
    __bf16* adjB = (__bf16*)w;
    __bf16* G0   = (__bf16*)(w + 33554432);
    __bf16* H1   = (__bf16*)(w + 33554432 + 4194304);
    __bf16* H2g  = (__bf16*)(w + 33554432 + 2 * 4194304);
    float*  H3   = (float*)(w + 33554432 + 3 * 4194304);
    float*  hid  = (float*)(w + 33554432 + 3 * 4194304 + 6291456);

    prep_k<<<10267, 256, 0, stream>>>(adj, adjB, X, W1, G0, hid);

    // stage 1: H1 = relu(adj @ G0^T + b1)          (W1 pre-applied in prep)
    gcn_k<0><<<512, 256, 0, stream>>>(adjB, G0, nullptr, b1, nullptr, H1, nullptr);
    // stage 2: H2g = (relu(adj @ H1^T @ W2 + b2)) @ W3, padded f=4
    gcn_k<1><<<512, 256, 0, stream>>>(adjB, H1, W2, b2, W3, H2g, nullptr);
    // stage 3: H3 = relu(adj @ H2g^T + b3), f<3, fp32
    gcn_k<2><<<512, 256, 0, stream>>>(adjB, H2g, nullptr, b3, nullptr, nullptr, H3);

    // FC head
    fc1p_k<<<dim3(64, 8), 256, 0, stream>>>(H3, Wfc, hid);
    fc2_k<<<dim3(16, 32), 256, 0, stream>>>(hid, bfc, Wout, bout, out);
}